// Round 1
// baseline (355.400 us; speedup 1.0000x reference)
//
#include <hip/hip_runtime.h>
#include <cstdint>
#include <cstddef>

#define N_DIM 4096
#define M_DIM 4096
#define D_DIM 4096

typedef unsigned short u16;
typedef u16   u16x8 __attribute__((ext_vector_type(8)));
typedef short s16x8 __attribute__((ext_vector_type(8)));   // 8 bf16 in shorts (4 VGPRs)
typedef float f32x4 __attribute__((ext_vector_type(4)));   // MFMA accumulator

// ---------- fp32 -> bf16 (RTNE) ----------
__device__ __forceinline__ u16 f2bf(float f) {
    union { float f; uint32_t u; } v; v.f = f;
    uint32_t u = v.u;
    uint32_t r = u + 0x7fffu + ((u >> 16) & 1u);
    return (u16)(r >> 16);
}

__global__ void convert_f32_bf16(const float* __restrict__ src, u16* __restrict__ dst) {
    size_t base = ((size_t)blockIdx.x * blockDim.x + threadIdx.x) * 8;
    const float4* s = (const float4*)(src + base);
    float4 a = s[0], b = s[1];
    u16x8 o;
    o[0] = f2bf(a.x); o[1] = f2bf(a.y); o[2] = f2bf(a.z); o[3] = f2bf(a.w);
    o[4] = f2bf(b.x); o[5] = f2bf(b.y); o[6] = f2bf(b.z); o[7] = f2bf(b.w);
    *(u16x8*)(dst + base) = o;
}

// ---------- async global->LDS, 16B per lane, wave-uniform LDS base ----------
__device__ __forceinline__ void g2l16(const u16* g, u16* l) {
    __builtin_amdgcn_global_load_lds(
        (const __attribute__((address_space(1))) void*)g,
        (__attribute__((address_space(3))) void*)l,
        16, 0, 0);
}

// ---------- 128x128 tile, BK=32, 16x16x32 bf16 MFMA (m97 structure) ----------
__global__ __launch_bounds__(256) void gemm_bt_bf16(
    const u16* __restrict__ A, const u16* __restrict__ B, float* __restrict__ C) {
    // NO padding: global_load_lds lands lane i at base + i*16 — layout must be
    // exactly contiguous row-major [128][32].
    __shared__ __align__(16) u16 As[128 * 32];
    __shared__ __align__(16) u16 Bs[128 * 32];

    const int tid   = threadIdx.x;
    const int lane  = tid & 63;
    const int wave  = tid >> 6;       // 0..3
    const int waveM = wave >> 1;      // 0..1 (row half)
    const int waveN = wave & 1;       // 0..1 (col half)

    const int rowBase = blockIdx.y * 128;   // N dim (A rows / C rows)
    const int colBase = blockIdx.x * 128;   // M dim (B rows / C cols)

    f32x4 acc[4][4] = {};

    // A/B-operand fragment addressing: elem[m = lane&15][k = (lane>>4)*8 + j]
    const int frag_row = lane & 15;
    const int frag_k   = (lane >> 4) * 8;

    for (int kt = 0; kt < D_DIM; kt += 32) {
        __syncthreads();  // previous iter's ds_reads done before overwrite
        const u16* Ag = A + (size_t)rowBase * D_DIM + kt;
        const u16* Bg = B + (size_t)colBase * D_DIM + kt;
        // tile = 128 rows x 64 B = 512 chunks of 16 B; 8 wave-calls of 64 lanes
        #pragma unroll
        for (int j = 0; j < 2; ++j) {
            int grp = j * 4 + wave;          // wave-uniform 0..7
            int c   = grp * 64 + lane;       // chunk id 0..511
            int r   = c >> 2;                // tile row
            int cc  = (c & 3) * 8;           // bf16 col offset within row
            g2l16(Ag + (size_t)r * D_DIM + cc, &As[grp * 512]);
            g2l16(Bg + (size_t)r * D_DIM + cc, &Bs[grp * 512]);
        }
        __syncthreads();  // compiler drains vmcnt before s_barrier

        s16x8 af[4], bf[4];
        #pragma unroll
        for (int mt = 0; mt < 4; ++mt) {
            int row = waveM * 64 + mt * 16 + frag_row;
            af[mt] = *(const s16x8*)&As[row * 32 + frag_k];
        }
        #pragma unroll
        for (int nt = 0; nt < 4; ++nt) {
            int row = waveN * 64 + nt * 16 + frag_row;
            bf[nt] = *(const s16x8*)&Bs[row * 32 + frag_k];
        }
        #pragma unroll
        for (int mt = 0; mt < 4; ++mt)
            #pragma unroll
            for (int nt = 0; nt < 4; ++nt)
                acc[mt][nt] = __builtin_amdgcn_mfma_f32_16x16x32_bf16(
                    af[mt], bf[nt], acc[mt][nt], 0, 0, 0);
    }

    // Epilogue. C/D layout (verified m89/m91): col = lane&15, row = (lane>>4)*4 + reg
    #pragma unroll
    for (int mt = 0; mt < 4; ++mt) {
        int gr0 = rowBase + waveM * 64 + mt * 16 + (lane >> 4) * 4;
        #pragma unroll
        for (int nt = 0; nt < 4; ++nt) {
            int gc = colBase + waveN * 64 + nt * 16 + (lane & 15);
            #pragma unroll
            for (int r = 0; r < 4; ++r)
                C[(size_t)(gr0 + r) * M_DIM + gc] = acc[mt][nt][r];
        }
    }
}

extern "C" void kernel_launch(void* const* d_in, const int* in_sizes, int n_in,
                              void* d_out, int out_size, void* d_ws, size_t ws_size,
                              hipStream_t stream) {
    const float* A32 = (const float*)d_in[0];   // [N, D] fp32
    const float* B32 = (const float*)d_in[1];   // [M, D] fp32
    float* C = (float*)d_out;                   // [N, M] fp32

    u16* Abf = (u16*)d_ws;                              // 32 MB
    u16* Bbf = Abf + (size_t)N_DIM * D_DIM;             // 32 MB

    // casts: 16.7M elems each, 8 per thread
    const int cvt_blocks = (N_DIM * (D_DIM / 8)) / 256; // 8192
    convert_f32_bf16<<<cvt_blocks, 256, 0, stream>>>(A32, Abf);
    convert_f32_bf16<<<cvt_blocks, 256, 0, stream>>>(B32, Bbf);

    dim3 grid(M_DIM / 128, N_DIM / 128);                // (32, 32)
    gemm_bt_bf16<<<grid, 256, 0, stream>>>(Abf, Bbf, C);
}